// Round 20
// baseline (1751.508 us; speedup 1.0000x reference)
//
#include <hip/hip_runtime.h>

#define B_N 16
#define T_N 15
#define CIN 64
#define COUT 128
#define HS 56
#define HWN 3136
#define NSG (16 * 128 * 28 * 28)

// PROVEN reference model (R10/R14, absmax=0.0):
//   conv: per-output flat sequential FMA chain, k-order (kh, kw, ci-innermost),
//         bias as separate rounded add. fma(+/-0,w,acc)==acc bit-exact.
//   elementwise/scan: per-op rounding, no FMA.
// Plateau analysis (R14/R16/R19 all ~63% VALU): weight SMEM traffic is
// 4 B per FMA-instruction -> ~8 B/cyc/CU scalar-fetch demand = the cap.
// This round: one weight stream drives TWO (b,b+1) x tiles per wave
// (acc[2][32]) -> 2 B/inst. Per-output chain unchanged.

// ---------- weight transpose: w[co][ci][kh][kw] -> wt4[tap][ci][co]
__global__ void wt_kernel(const float* __restrict__ w, float* __restrict__ wt4) {
    int i = blockIdx.x * 256 + threadIdx.x;  // 0 .. 73727
    if (i >= COUT * 576) return;
    int co = i / 576;
    int r = i - co * 576;      // ci*9 + kh*3 + kw
    int ci = r / 9;
    int kk = r - ci * 9;       // kh*3+kw
    wt4[((size_t)kk * CIN + ci) * COUT + co] = w[i];
}

// ---------- conv: 4 waves x (64 px lanes x 32 co x 2 batches) ----------
__global__ __launch_bounds__(256) void conv_sgpr2(
    const float* __restrict__ x, const float* __restrict__ wt4,
    const float* __restrict__ bias, float* __restrict__ obuf,
    int t0, int nz)
{
    __shared__ float xs[2 * CIN * 100];   // two [64][10][10] tiles, zero halo

    // XCD-chunked swizzle (nz divisible by 8)
    const int bid = blockIdx.x;
    const int z = (bid & 7) * (nz >> 3) + (bid >> 3);

    const int tile = z % 49;
    const int u = z / 49;
    const int bp = u & 7;            // b-pair: b0 = 2*bp
    const int tc = u >> 3;
    const int b0 = bp * 2;

    const int ty = tile / 7, tx = tile - ty * 7;
    const int h0 = ty * 8, w0c = tx * 8;

    const int tid = threadIdx.x;

    // ---- stage two x tiles [64][10][10], +0.0f padding ----
    const float* xb0 = x + ((size_t)(b0 * T_N + (t0 + tc)) * CIN) * HWN;
    const float* xb1 = x + ((size_t)((b0 + 1) * T_N + (t0 + tc)) * CIN) * HWN;
    for (int i = tid; i < 2 * CIN * 100; i += 256) {
        int q = i / 6400;                // which tile
        int r = i - q * 6400;
        int ci = r / 100;
        int rem = r - ci * 100;
        int rr = rem / 10;
        int cc = rem - rr * 10;
        int gh = h0 - 1 + rr;
        int gw = w0c - 1 + cc;
        float v = 0.0f;
        if ((unsigned)gh < (unsigned)HS && (unsigned)gw < (unsigned)HS)
            v = (q ? xb1 : xb0)[(size_t)ci * HWN + gh * HS + gw];
        xs[i] = v;
    }
    __syncthreads();

    const int lane = tid & 63;
    const int wv = __builtin_amdgcn_readfirstlane(tid >> 6);  // 0..3, uniform
    const int co0 = wv * 32;
    const int lh = lane >> 3;       // local row 0..7
    const int lw = lane & 7;        // local col 0..7

    float acc0[32], acc1[32];
#pragma unroll
    for (int j = 0; j < 32; ++j) { acc0[j] = 0.0f; acc1[j] = 0.0f; }

    for (int kh = 0; kh < 3; ++kh) {
        for (int kw = 0; kw < 3; ++kw) {
            const int xoff = (lh + kh) * 10 + (lw + kw);
            // uniform weight base for this (tap, wave)
            const float* wk = wt4 + ((size_t)(kh * 3 + kw) * CIN) * COUT + co0;
            for (int c8 = 0; c8 < 8; ++c8) {
                float xv0[8], xv1[8];
#pragma unroll
                for (int k = 0; k < 8; ++k) {
                    xv0[k] = xs[(c8 * 8 + k) * 100 + xoff];
                    xv1[k] = xs[6400 + (c8 * 8 + k) * 100 + xoff];
                }
#pragma unroll
                for (int k = 0; k < 8; ++k) {
                    const int ci = c8 * 8 + k;
#pragma unroll
                    for (int j = 0; j < 32; ++j) {
                        // one SGPR weight feeds both batches: 2B SMEM / FMA
                        const float wj = wk[ci * COUT + j];
                        acc0[j] = fmaf(xv0[k], wj, acc0[j]);
                        acc1[j] = fmaf(xv1[k], wj, acc1[j]);
                    }
                }
            }
        }
    }

    // bias (separate rounded add) + stores (coalesced px lanes)
    const int h = h0 + lh;
    const int wq = w0c + lw;
    const size_t ob0 = ((size_t)(tc * 16 + b0) * COUT + co0) * HWN
                     + (size_t)h * HS + wq;
    const size_t ob1 = ((size_t)(tc * 16 + b0 + 1) * COUT + co0) * HWN
                     + (size_t)h * HS + wq;
#pragma unroll
    for (int j = 0; j < 32; ++j) {
        const float bv = bias[co0 + j];
        obuf[ob0 + (size_t)j * HWN] = __fadd_rn(acc0[j], bv);
        obuf[ob1 + (size_t)j * HWN] = __fadd_rn(acc1[j], bv);
    }
}

// ---------- recurrence, strict fp32, in-kernel t-loop ----------
__global__ __launch_bounds__(256) void rec32(
    const float* __restrict__ cvbuf, const float* __restrict__ fcw,
    const float* __restrict__ fcb, float* __restrict__ stateD,
    unsigned* __restrict__ stateS, float* __restrict__ out,
    int t0, int nt, int doLoad, int doStore)
{
    const int idx = blockIdx.x * 256 + threadIdx.x;  // 16*128*784 sites
    const int pw = idx % 28;
    int tmp = idx / 28;
    const int ph = tmp % 28;
    tmp /= 28;
    const int co = tmp & 127;
    const int b = tmp >> 7;

    const size_t g = (size_t)idx;

    const float w0 = fcw[0], w1 = fcw[1], w2 = fcw[2], fb = fcb[0];

    float u[4], m3[4], s[4];
    if (doLoad) {
        unsigned sm = stateS[g];
#pragma unroll
        for (int p = 0; p < 4; ++p) {
            u[p] = stateD[(size_t)p * NSG + g];
            m3[p] = stateD[(size_t)(4 + p) * NSG + g];
            s[p] = (float)((sm >> p) & 1u);
        }
    } else {
#pragma unroll
        for (int p = 0; p < 4; ++p) { u[p] = 0.0f; m3[p] = 0.0f; s[p] = 0.0f; }
    }

    const int h0 = ph * 2, wc0 = pw * 2;

    for (int tc = 0; tc < nt; ++tc) {
        const size_t cbase = ((size_t)(tc * 16 + b) * COUT + co) * HWN
                           + (size_t)h0 * HS + wc0;
        const float cv[4] = {cvbuf[cbase], cvbuf[cbase + 1],
                             cvbuf[cbase + HS], cvbuf[cbase + HS + 1]};

#pragma unroll
        for (int p = 0; p < 4; ++p) {
            float e0 = __fadd_rn(__fadd_rn(__fmul_rn(u[p], w0), __fmul_rn(u[p], w1)),
                                 __fmul_rn(u[p], w2));
            float x4 = __fadd_rn(e0, fb);
            float dd = __fmul_rn(0.2f, __fsub_rn(1.0f, s[p]));
            u[p]  = __fadd_rn(__fmul_rn(u[p], dd), cv[p]);
            m3[p] = __fadd_rn(__fmul_rn(m3[p], dd), x4);
            float e1 = __fadd_rn(__fadd_rn(__fmul_rn(u[p], w0), __fmul_rn(u[p], w1)),
                                 __fmul_rn(u[p], w2));
            float mem1 = __fadd_rn(__fadd_rn(e1, fb), m3[p]);
            s[p] = (__fsub_rn(mem1, 0.8f) > 0.0f) ? 1.0f : 0.0f;
        }

        float pooled = 0.25f * (((s[0] + s[1]) + s[2]) + s[3]);
        out[(((size_t)b * T_N + (t0 + tc)) * COUT + co) * 784 + ph * 28 + pw] = pooled;
    }

    if (doStore) {
        unsigned sm = 0;
#pragma unroll
        for (int p = 0; p < 4; ++p) {
            stateD[(size_t)p * NSG + g] = u[p];
            stateD[(size_t)(4 + p) * NSG + g] = m3[p];
            sm |= (s[p] > 0.5f) ? (1u << p) : 0u;
        }
        stateS[g] = sm;
    }
}

extern "C" void kernel_launch(void* const* d_in, const int* in_sizes, int n_in,
                              void* d_out, int out_size, void* d_ws, size_t ws_size,
                              hipStream_t stream) {
    const float* x     = (const float*)d_in[0];
    const float* cw    = (const float*)d_in[1];
    const float* cbias = (const float*)d_in[2];
    const float* fcw   = (const float*)d_in[3];
    const float* fcb   = (const float*)d_in[4];
    float* out = (float*)d_out;

    const size_t wtB   = (size_t)576 * COUT * sizeof(float);        // 294 KB
    const size_t convT = (size_t)B_N * COUT * HWN * sizeof(float);  // 25.69 MB / t
    const size_t statB = (size_t)NSG * 8 * sizeof(float)
                       + (size_t)NSG * sizeof(unsigned);            // ~57.8 MB

    int Tc;
    if (wtB + (size_t)T_N * convT <= ws_size) {
        Tc = T_N;                                   // no state spill needed
    } else if (ws_size > wtB + statB + convT) {
        Tc = (int)((ws_size - wtB - statB) / convT);
        if (Tc > T_N) Tc = T_N;
    } else {
        return;  // ws unusably small
    }

    float* wt4 = (float*)d_ws;
    float* convbuf = (float*)((char*)d_ws + wtB);
    float* stateD = (float*)((char*)d_ws + wtB + (size_t)Tc * convT);
    unsigned* stateS = (unsigned*)((char*)stateD + (size_t)NSG * 8 * sizeof(float));

    wt_kernel<<<(COUT * 576 + 255) / 256, 256, 0, stream>>>(cw, wt4);

    for (int t0 = 0; t0 < T_N; t0 += Tc) {
        const int nt = (T_N - t0 < Tc) ? (T_N - t0) : Tc;
        const int nz = nt * 8 * 49;                 // b-pairs; divisible by 8
        conv_sgpr2<<<nz, 256, 0, stream>>>(x, wt4, cbias, convbuf, t0, nz);
        rec32<<<NSG / 256, 256, 0, stream>>>(
            convbuf, fcw, fcb, stateD, stateS, out,
            t0, nt, t0 > 0 ? 1 : 0, (t0 + nt) < T_N ? 1 : 0);
    }
}